// Round 5
// baseline (110.747 us; speedup 1.0000x reference)
//
#include <hip/hip_runtime.h>

#define BSZ    64
#define NF     4
#define NCLS   4
#define PLO    256
#define PHI    16384
#define KN     9
#define W27    27
#define SPLITS 4

__global__ __launch_bounds__(256, 4) void rect_up_kernel(
    const float* __restrict__ x,         // (B, NF*PLO)
    const float* __restrict__ orog,      // (B, PHI, 2)
    const float* __restrict__ wmap,      // (NCLS, NF, PHI, KN, 3)
    const float* __restrict__ bias_low,  // (NCLS, NF, PLO)
    const float* __restrict__ bias_high, // (NCLS, NF, PHI)
    const float* __restrict__ bias_orog, // (NCLS, 2, PHI)
    const int*   __restrict__ cls_ids,   // (B,)
    const int*   __restrict__ nb,        // (PHI, KN)
    float* __restrict__ out)             // (B, NF, PHI)
{
    // per-wave private staging regions -> no __syncthreads anywhere
    __shared__ float wstage[4][64 * W27];   // 27648 B

    // XCD-aware decode: class c's blocks land only on XCDs {c, c+4};
    // the 4 splits of one (cls,chunk) share that XCD pair's L2 slice.
    const int pos   = blockIdx.x;           // 0..1023
    const int xslot = pos & 7;
    const int cls   = xslot & 3;
    const int sh    = xslot >> 2;
    const int seq   = pos >> 3;             // 0..127
    const int chunk = seq >> 1;             // 0..63
    const int split = sh | ((seq & 1) << 1);// 0..3

    const int t     = threadIdx.x;
    const int wave  = t >> 6;
    const int lane  = t & 63;
    const int p     = chunk * 256 + t;

    // ---- class membership mask (wave width == BSZ == 64) ---------------
    const unsigned long long cmask = __ballot(cls_ids[lane] == cls);

    // ---- batch-invariant neighbor geometry -----------------------------
    const int pi = p >> 7, pj = p & 127;
    const int cr0 = (pi - 2 < 0 ? 0 : pi - 2) >> 3;
    const int cr1 = (pi + 2 > 127 ? 127 : pi + 2) >> 3;
    const int cc0 = (pj - 2 < 0 ? 0 : pj - 2) >> 3;
    const int cc1 = (pj + 2 > 127 ? 127 : pj + 2) >> 3;
    int cells[4];
    cells[0] = cr0 * 16 + cc0;  cells[1] = cr0 * 16 + cc1;
    cells[2] = cr1 * 16 + cc0;  cells[3] = cr1 * 16 + cc1;

    int nbOff[KN], sel[KN];
    #pragma unroll
    for (int k = 0; k < KN; ++k) {
        const int n = nb[p * KN + k];
        nbOff[k] = n * 8;
        sel[k] = (((n >> 7) >> 3) != cr0 ? 2 : 0) | (((n & 127) >> 3) != cc0 ? 1 : 0);
    }

    // ---- batch scan state ----------------------------------------------
    unsigned long long m = cmask;
    int ord = 0;
    auto nextb = [&]() -> int {
        while (m) {
            const int b = __ffsll((unsigned long long)m) - 1;
            m &= m - 1;
            const bool take = (ord == split);
            ord = (ord + 1 == SPLITS) ? 0 : ord + 1;
            if (take) return b;
        }
        return -1;
    };

    int b = nextb();
    if (b < 0) return;                      // uniform across block

    // ---- prefetch first batch's orog BEFORE weight staging -------------
    float o0[KN], o1[KN];
    {
        const char* ob = (const char*)orog + (size_t)b * (PHI * 8);
        #pragma unroll
        for (int k = 0; k < KN; ++k) {
            const float2 v = *reinterpret_cast<const float2*>(ob + nbOff[k]);
            o0[k] = v.x; o1[k] = v.y;
        }
    }

    // ---- early bias loads (independent of weights) ---------------------
    float yob0[KN], yob1[KN];
    #pragma unroll
    for (int k = 0; k < KN; ++k) {
        const int n = nbOff[k] >> 3;
        yob0[k] = bias_orog[(cls * 2 + 0) * PHI + n];
        yob1[k] = bias_orog[(cls * 2 + 1) * PHI + n];
    }
    float bh[NF], blv[NF][4];
    #pragma unroll
    for (int f = 0; f < NF; ++f) {
        bh[f] = bias_high[(cls * NF + f) * PHI + p];
        #pragma unroll
        for (int j = 0; j < 4; ++j)
            blv[f][j] = bias_low[(cls * NF + f) * PLO + cells[j]];
    }

    // ---- weights: per-wave staging, software-pipelined across f --------
    // round f: ds_write(pre_f) ; issue global loads pre_{f+1} ; unpack f
    float wcy[NF][4], w1[NF][KN], w2[NF][KN];
    float4* d4 = reinterpret_cast<float4*>(&wstage[wave][0]);
    float4 pre[7];
    {
        const float4* s4 = reinterpret_cast<const float4*>(
            wmap + ((size_t)(cls * NF + 0) * PHI + chunk * 256 + wave * 64) * W27);
        #pragma unroll
        for (int i2 = 0; i2 < 7; ++i2) {
            const int idx = lane + i2 * 64;            // 432 float4 per wave
            if (idx < (64 * W27) / 4) pre[i2] = s4[idx];
        }
    }
    #pragma unroll
    for (int f = 0; f < NF; ++f) {
        #pragma unroll
        for (int i2 = 0; i2 < 7; ++i2) {
            const int idx = lane + i2 * 64;
            if (idx < (64 * W27) / 4) d4[idx] = pre[i2];
        }
        if (f < NF - 1) {                              // prefetch next f
            const float4* s4 = reinterpret_cast<const float4*>(
                wmap + ((size_t)(cls * NF + f + 1) * PHI + chunk * 256 + wave * 64) * W27);
            #pragma unroll
            for (int i2 = 0; i2 < 7; ++i2) {
                const int idx = lane + i2 * 64;
                if (idx < (64 * W27) / 4) pre[i2] = s4[idx];
            }
        }
        // wave-local RAW through LDS: DS ops are wave-ordered
        #pragma unroll
        for (int j = 0; j < 4; ++j) wcy[f][j] = 0.0f;
        #pragma unroll
        for (int k = 0; k < KN; ++k) {
            const float w0 = wstage[wave][lane * W27 + 3 * k];
            w1[f][k] = wstage[wave][lane * W27 + 3 * k + 1];
            w2[f][k] = wstage[wave][lane * W27 + 3 * k + 2];
            #pragma unroll
            for (int j = 0; j < 4; ++j)
                wcy[f][j] += (sel[k] == j) ? w0 : 0.0f;
        }
    }

    // ---- fold biases into accumulator init -----------------------------
    float accInit[NF];
    #pragma unroll
    for (int f = 0; f < NF; ++f) {
        float a = bh[f];
        #pragma unroll
        for (int k = 0; k < KN; ++k)
            a -= yob0[k] * w1[f][k] + yob1[k] * w2[f][k];
        #pragma unroll
        for (int j = 0; j < 4; ++j)
            a -= blv[f][j] * wcy[f][j];
        accInit[f] = a;
    }

    // ---- batch loop: barrier-free, orog prefetched one batch ahead -----
    while (true) {
        const int bn = nextb();
        float n0[KN], n1[KN];
        if (bn >= 0) {
            const char* ob = (const char*)orog + (size_t)bn * (PHI * 8);
            #pragma unroll
            for (int k = 0; k < KN; ++k) {
                const float2 v = *reinterpret_cast<const float2*>(ob + nbOff[k]);
                n0[k] = v.x; n1[k] = v.y;
            }
        }

        const float* xb = x + b * (NF * PLO);
        #pragma unroll
        for (int f = 0; f < NF; ++f) {
            float acc = accInit[f];
            #pragma unroll
            for (int j = 0; j < 4; ++j)
                acc += xb[f * PLO + cells[j]] * wcy[f][j];
            #pragma unroll
            for (int k = 0; k < KN; ++k)
                acc += o0[k] * w1[f][k] + o1[k] * w2[f][k];
            out[((size_t)b * NF + f) * PHI + p] = acc;   // cached store
        }

        if (bn < 0) break;
        b = bn;
        #pragma unroll
        for (int k = 0; k < KN; ++k) { o0[k] = n0[k]; o1[k] = n1[k]; }
    }
}

extern "C" void kernel_launch(void* const* d_in, const int* in_sizes, int n_in,
                              void* d_out, int out_size, void* d_ws, size_t ws_size,
                              hipStream_t stream) {
    const float* x         = (const float*)d_in[0];
    const float* orog      = (const float*)d_in[1];
    const float* wmap      = (const float*)d_in[2];
    const float* bias_low  = (const float*)d_in[3];
    const float* bias_high = (const float*)d_in[4];
    const float* bias_orog = (const float*)d_in[5];
    const int*   cls_ids   = (const int*)d_in[6];
    const int*   nb        = (const int*)d_in[7];
    float* out = (float*)d_out;

    // grid: NCLS x 64 chunks x SPLITS = 1024 blocks (XCD-swizzled decode)
    dim3 grid(NCLS * (PHI / 256) * SPLITS);
    dim3 block(256);
    rect_up_kernel<<<grid, block, 0, stream>>>(
        x, orog, wmap, bias_low, bias_high, bias_orog, cls_ids, nb, out);
}

// Round 6
// 37.672 us; speedup vs baseline: 2.9398x; 2.9398x over previous
//
#include <hip/hip_runtime.h>

#define BSZ    64
#define NF     4
#define NCLS   4
#define PLO    256
#define PHI    16384
#define KN     9
#define W27    27
#define SPLITS 3

__global__ __launch_bounds__(256, 3) void rect_up_kernel(
    const float* __restrict__ x,         // (B, NF*PLO)
    const float* __restrict__ orog,      // (B, PHI, 2)
    const float* __restrict__ wmap,      // (NCLS, NF, PHI, KN, 3)
    const float* __restrict__ bias_low,  // (NCLS, NF, PLO)
    const float* __restrict__ bias_high, // (NCLS, NF, PHI)
    const float* __restrict__ bias_orog, // (NCLS, 2, PHI)
    const int*   __restrict__ cls_ids,   // (B,)
    const int*   __restrict__ nb,        // (PHI, KN)
    float* __restrict__ out)             // (B, NF, PHI)
{
    // per-wave private staging regions -> no __syncthreads anywhere
    __shared__ float wstage[4][64 * W27];   // 27648 B

    const int bid   = blockIdx.x;
    const int cls   = bid & (NCLS - 1);
    const int chunk = (bid >> 2) & 63;
    const int split = bid >> 8;             // 0..SPLITS-1
    const int t     = threadIdx.x;
    const int wave  = t >> 6;
    const int lane  = t & 63;
    const int p     = chunk * 256 + t;

    // ---- issue f=0 weight loads FIRST (no dependencies) ----------------
    float4 pre[7];
    {
        const float4* s4 = reinterpret_cast<const float4*>(
            wmap + ((size_t)(cls * NF + 0) * PHI + chunk * 256 + wave * 64) * W27);
        #pragma unroll
        for (int i2 = 0; i2 < 7; ++i2) {
            const int idx = lane + i2 * 64;        // 432 float4 per wave region
            if (idx < (64 * W27) / 4) pre[i2] = s4[idx];
        }
    }

    // ---- class membership mask (wave width == BSZ == 64) ---------------
    const unsigned long long cmask = __ballot(cls_ids[lane] == cls);

    // ---- batch-invariant neighbor geometry -----------------------------
    const int pi = p >> 7, pj = p & 127;
    const int cr0 = (pi - 2 < 0 ? 0 : pi - 2) >> 3;
    const int cr1 = (pi + 2 > 127 ? 127 : pi + 2) >> 3;
    const int cc0 = (pj - 2 < 0 ? 0 : pj - 2) >> 3;
    const int cc1 = (pj + 2 > 127 ? 127 : pj + 2) >> 3;
    int cells[4];
    cells[0] = cr0 * 16 + cc0;  cells[1] = cr0 * 16 + cc1;
    cells[2] = cr1 * 16 + cc0;  cells[3] = cr1 * 16 + cc1;

    int nbOff[KN], sel[KN];
    #pragma unroll
    for (int k = 0; k < KN; ++k) {
        const int n = nb[p * KN + k];
        nbOff[k] = n * 8;
        sel[k] = (((n >> 7) >> 3) != cr0 ? 2 : 0) | (((n & 127) >> 3) != cc0 ? 1 : 0);
    }

    // early bias_orog gathers: fly under the weight stream
    float yob0[KN], yob1[KN];
    #pragma unroll
    for (int k = 0; k < KN; ++k) {
        const int n = nbOff[k] >> 3;
        yob0[k] = bias_orog[(cls * 2 + 0) * PHI + n];
        yob1[k] = bias_orog[(cls * 2 + 1) * PHI + n];
    }

    // ---- batch scan state ----------------------------------------------
    unsigned long long m = cmask;
    int ord = 0;
    auto nextb = [&]() -> int {
        while (m) {
            const int b = __ffsll((unsigned long long)m) - 1;
            m &= m - 1;
            const bool take = (ord == split);
            ord = (ord + 1 == SPLITS) ? 0 : ord + 1;
            if (take) return b;
        }
        return -1;
    };

    int b = nextb();
    if (b < 0) return;                      // uniform across block

    // ---- weights: per-wave staging, f-rounds software-pipelined --------
    // round f: ds_write(pre_f); issue global loads pre_{f+1}; unpack f;
    //          fold per-f biases into accInit (bh/blv loaded in-round).
    float wcy[NF][4], w1[NF][KN], w2[NF][KN], accInit[NF];
    float4* d4 = reinterpret_cast<float4*>(&wstage[wave][0]);
    #pragma unroll
    for (int f = 0; f < NF; ++f) {
        #pragma unroll
        for (int i2 = 0; i2 < 7; ++i2) {
            const int idx = lane + i2 * 64;
            if (idx < (64 * W27) / 4) d4[idx] = pre[i2];
        }
        if (f < NF - 1) {                              // prefetch next f
            const float4* s4 = reinterpret_cast<const float4*>(
                wmap + ((size_t)(cls * NF + f + 1) * PHI + chunk * 256 + wave * 64) * W27);
            #pragma unroll
            for (int i2 = 0; i2 < 7; ++i2) {
                const int idx = lane + i2 * 64;
                if (idx < (64 * W27) / 4) pre[i2] = s4[idx];
            }
        }
        // per-f bias loads (die within the round)
        const float bhf = bias_high[(cls * NF + f) * PHI + p];
        float blf[4];
        #pragma unroll
        for (int j = 0; j < 4; ++j)
            blf[j] = bias_low[(cls * NF + f) * PLO + cells[j]];

        // wave-local RAW through LDS: DS ops are wave-ordered
        #pragma unroll
        for (int j = 0; j < 4; ++j) wcy[f][j] = 0.0f;
        #pragma unroll
        for (int k = 0; k < KN; ++k) {
            const float w0 = wstage[wave][lane * W27 + 3 * k];
            w1[f][k] = wstage[wave][lane * W27 + 3 * k + 1];
            w2[f][k] = wstage[wave][lane * W27 + 3 * k + 2];
            #pragma unroll
            for (int j = 0; j < 4; ++j)
                wcy[f][j] += (sel[k] == j) ? w0 : 0.0f;
        }
        float a = bhf;
        #pragma unroll
        for (int k = 0; k < KN; ++k)
            a -= yob0[k] * w1[f][k] + yob1[k] * w2[f][k];
        #pragma unroll
        for (int j = 0; j < 4; ++j)
            a -= blf[j] * wcy[f][j];
        accInit[f] = a;
    }

    // ---- first batch's orog: issued here, flies under nothing heavy ----
    float o0[KN], o1[KN];
    {
        const char* ob = (const char*)orog + (size_t)b * (PHI * 8);
        #pragma unroll
        for (int k = 0; k < KN; ++k) {
            const float2 v = *reinterpret_cast<const float2*>(ob + nbOff[k]);
            o0[k] = v.x; o1[k] = v.y;
        }
    }

    // ---- batch loop: barrier-free, orog prefetched one batch ahead -----
    while (true) {
        const int bn = nextb();
        float n0[KN], n1[KN];
        if (bn >= 0) {
            const char* ob = (const char*)orog + (size_t)bn * (PHI * 8);
            #pragma unroll
            for (int k = 0; k < KN; ++k) {
                const float2 v = *reinterpret_cast<const float2*>(ob + nbOff[k]);
                n0[k] = v.x; n1[k] = v.y;
            }
        }

        const float* xb = x + b * (NF * PLO);
        #pragma unroll
        for (int f = 0; f < NF; ++f) {
            float acc = accInit[f];
            #pragma unroll
            for (int j = 0; j < 4; ++j)
                acc += xb[f * PLO + cells[j]] * wcy[f][j];
            #pragma unroll
            for (int k = 0; k < KN; ++k)
                acc += o0[k] * w1[f][k] + o1[k] * w2[f][k];
            out[((size_t)b * NF + f) * PHI + p] = acc;   // cached store
        }

        if (bn < 0) break;
        b = bn;
        #pragma unroll
        for (int k = 0; k < KN; ++k) { o0[k] = n0[k]; o1[k] = n1[k]; }
    }
}

extern "C" void kernel_launch(void* const* d_in, const int* in_sizes, int n_in,
                              void* d_out, int out_size, void* d_ws, size_t ws_size,
                              hipStream_t stream) {
    const float* x         = (const float*)d_in[0];
    const float* orog      = (const float*)d_in[1];
    const float* wmap      = (const float*)d_in[2];
    const float* bias_low  = (const float*)d_in[3];
    const float* bias_high = (const float*)d_in[4];
    const float* bias_orog = (const float*)d_in[5];
    const int*   cls_ids   = (const int*)d_in[6];
    const int*   nb        = (const int*)d_in[7];
    float* out = (float*)d_out;

    // grid: NCLS classes x 64 p-chunks x SPLITS batch-splits = 768 blocks
    dim3 grid(NCLS * (PHI / 256) * SPLITS);
    dim3 block(256);
    rect_up_kernel<<<grid, block, 0, stream>>>(
        x, orog, wmap, bias_low, bias_high, bias_orog, cls_ids, nb, out);
}

// Round 7
// 37.219 us; speedup vs baseline: 2.9755x; 1.0122x over previous
//
#include <hip/hip_runtime.h>

#define BSZ    64
#define NF     4
#define NCLS   4
#define PLO    256
#define PHI    16384
#define KN     9
#define W27    27
#define CPX    64               // pixels per block

__global__ __launch_bounds__(256, 3) void rect_up_kernel(
    const float* __restrict__ x,         // (B, NF*PLO)
    const float* __restrict__ orog,      // (B, PHI, 2)
    const float* __restrict__ wmap,      // (NCLS, NF, PHI, KN, 3)
    const float* __restrict__ bias_low,  // (NCLS, NF, PLO)
    const float* __restrict__ bias_high, // (NCLS, NF, PHI)
    const float* __restrict__ bias_orog, // (NCLS, 2, PHI)
    const int*   __restrict__ cls_ids,   // (B,)
    const int*   __restrict__ nb,        // (PHI, KN)
    float* __restrict__ out)             // (B, NF, PHI)
{
    // per-wave private staging region -> zero barriers in the kernel
    __shared__ float wstage[NF][CPX * W27];   // 27648 B

    const int bid   = blockIdx.x;
    const int cls   = bid & (NCLS - 1);
    const int chunk = bid >> 2;              // 0..255
    const int t     = threadIdx.x;
    const int f     = t >> 6;                // wave index == feature
    const int lane  = t & 63;
    const int p     = chunk * CPX + lane;    // this thread's pixel

    // ---- issue this wave's weight staging FIRST (addr depends on bid only)
    {
        const float4* s4 = reinterpret_cast<const float4*>(
            wmap + ((size_t)(cls * NF + f) * PHI + chunk * CPX) * W27);
        float4* d4 = reinterpret_cast<float4*>(&wstage[f][0]);
        #pragma unroll
        for (int i = 0; i < 7; ++i) {
            const int idx = lane + i * 64;         // 432 float4 per wave
            if (idx < (CPX * W27) / 4) d4[idx] = s4[idx];
        }
    }

    // ---- class membership mask (wave width == BSZ == 64) ---------------
    const unsigned long long cmask = __ballot(cls_ids[lane] == cls);
    if (cmask == 0ULL) return;               // uniform

    // ---- batch-invariant neighbor geometry -----------------------------
    const int pi = p >> 7, pj = p & 127;
    const int cr0 = (pi - 2 < 0 ? 0 : pi - 2) >> 3;
    const int cc0 = (pj - 2 < 0 ? 0 : pj - 2) >> 3;
    const int cr1 = (pi + 2 > 127 ? 127 : pi + 2) >> 3;
    const int cc1 = (pj + 2 > 127 ? 127 : pj + 2) >> 3;
    int cells[4];
    cells[0] = cr0 * 16 + cc0;  cells[1] = cr0 * 16 + cc1;
    cells[2] = cr1 * 16 + cc0;  cells[3] = cr1 * 16 + cc1;

    int nbOff[KN], sel[KN];
    #pragma unroll
    for (int k = 0; k < KN; ++k) {
        const int n = nb[p * KN + k];
        nbOff[k] = n * 8;                    // byte offset into a batch's orog
        sel[k] = (((n >> 7) >> 3) != cr0 ? 2 : 0) | (((n & 127) >> 3) != cc0 ? 1 : 0);
    }

    // ---- bias gathers (fly under the weight stream) --------------------
    float yob0[KN], yob1[KN];
    #pragma unroll
    for (int k = 0; k < KN; ++k) {
        const int n = nbOff[k] >> 3;
        yob0[k] = bias_orog[(cls * 2 + 0) * PHI + n];
        yob1[k] = bias_orog[(cls * 2 + 1) * PHI + n];
    }
    const float bhf = bias_high[(cls * NF + f) * PHI + p];
    float blf[4];
    #pragma unroll
    for (int j = 0; j < 4; ++j)
        blf[j] = bias_low[(cls * NF + f) * PLO + cells[j]];

    // ---- unpack this thread's 27 weights (wave-local LDS RAW) ----------
    float w1[KN], w2[KN], wcy[4] = {0.f, 0.f, 0.f, 0.f};
    #pragma unroll
    for (int k = 0; k < KN; ++k) {
        const float w0 = wstage[f][lane * W27 + 3 * k];
        w1[k] = wstage[f][lane * W27 + 3 * k + 1];
        w2[k] = wstage[f][lane * W27 + 3 * k + 2];
        #pragma unroll
        for (int j = 0; j < 4; ++j)
            wcy[j] += (sel[k] == j) ? w0 : 0.0f;   // static idx only (no scratch)
    }

    // ---- fold all biases into accumulator init -------------------------
    float acc0 = bhf;
    #pragma unroll
    for (int k = 0; k < KN; ++k)
        acc0 -= yob0[k] * w1[k] + yob1[k] * w2[k];
    #pragma unroll
    for (int j = 0; j < 4; ++j)
        acc0 -= blf[j] * wcy[j];

    // ---- batch loop over ALL batches of this class (SPLITS=1) ----------
    unsigned long long m = cmask;
    int b = __ffsll(m) - 1;  m &= m - 1;

    float o0[KN], o1[KN];
    {
        const char* ob = (const char*)orog + (size_t)b * (PHI * 8);
        #pragma unroll
        for (int k = 0; k < KN; ++k) {
            const float2 v = *reinterpret_cast<const float2*>(ob + nbOff[k]);
            o0[k] = v.x; o1[k] = v.y;
        }
    }

    while (true) {
        const int bn = m ? (__ffsll(m) - 1) : -1;
        if (m) m &= m - 1;

        float n0[KN], n1[KN];
        if (bn >= 0) {                       // prefetch next batch's orog
            const char* ob = (const char*)orog + (size_t)bn * (PHI * 8);
            #pragma unroll
            for (int k = 0; k < KN; ++k) {
                const float2 v = *reinterpret_cast<const float2*>(ob + nbOff[k]);
                n0[k] = v.x; n1[k] = v.y;
            }
        }

        const float* xb = x + b * (NF * PLO) + f * PLO;
        float acc = acc0;
        #pragma unroll
        for (int j = 0; j < 4; ++j)
            acc += xb[cells[j]] * wcy[j];
        #pragma unroll
        for (int k = 0; k < KN; ++k)
            acc += o0[k] * w1[k] + o1[k] * w2[k];
        out[((size_t)b * NF + f) * PHI + p] = acc;

        if (bn < 0) break;
        b = bn;
        #pragma unroll
        for (int k = 0; k < KN; ++k) { o0[k] = n0[k]; o1[k] = n1[k]; }
    }
}

extern "C" void kernel_launch(void* const* d_in, const int* in_sizes, int n_in,
                              void* d_out, int out_size, void* d_ws, size_t ws_size,
                              hipStream_t stream) {
    const float* x         = (const float*)d_in[0];
    const float* orog      = (const float*)d_in[1];
    const float* wmap      = (const float*)d_in[2];
    const float* bias_low  = (const float*)d_in[3];
    const float* bias_high = (const float*)d_in[4];
    const float* bias_orog = (const float*)d_in[5];
    const int*   cls_ids   = (const int*)d_in[6];
    const int*   nb        = (const int*)d_in[7];
    float* out = (float*)d_out;

    // grid: NCLS classes x 256 chunks of 64 pixels = 1024 blocks;
    // block: 4 waves, wave w handles feature f=w for the chunk's 64 pixels.
    dim3 grid(NCLS * (PHI / CPX));
    dim3 block(256);
    rect_up_kernel<<<grid, block, 0, stream>>>(
        x, orog, wmap, bias_low, bias_high, bias_orog, cls_ids, nb, out);
}

// Round 8
// 25.203 us; speedup vs baseline: 4.3942x; 1.4768x over previous
//
#include <hip/hip_runtime.h>

#define BSZ    64
#define NF     4
#define NCLS   4
#define PLO    256
#define PHI    16384
#define KN     9
#define W27    27
#define CPX    64              // pixels per block (half a 128-row)
#define TH     5               // tile rows  (pi-2 .. pi+2)
#define TW     68              // tile cols  (j0-2 .. j0+65)
#define TSL    (TH * TW)       // 340 float2 slots
#define XSL    80              // NF * 2 cell-rows * 10 cell-cols
#define ARENA_F 6912           // floats: max(w-stage 4*1728, 2*680+2*80)

__global__ __launch_bounds__(256, 4) void rect_up_kernel(
    const float* __restrict__ x,         // (B, NF*PLO)
    const float* __restrict__ orog,      // (B, PHI, 2)
    const float* __restrict__ wmap,      // (NCLS, NF, PHI, KN, 3)
    const float* __restrict__ bias_low,  // (NCLS, NF, PLO)
    const float* __restrict__ bias_high, // (NCLS, NF, PHI)
    const float* __restrict__ bias_orog, // (NCLS, 2, PHI)
    const int*   __restrict__ cls_ids,   // (B,)
    const int*   __restrict__ nb,        // (PHI, KN)
    float* __restrict__ out)             // (B, NF, PHI)
{
    __shared__ float arena[ARENA_F];     // phase 1: w-stage; phase 2: tiles

    const int bid   = blockIdx.x;
    const int cls   = bid & 3;
    const int chunk = bid >> 2;          // 0..255
    const int t     = threadIdx.x;
    const int f     = t >> 6;            // wave == feature
    const int lane  = t & 63;
    const int p     = chunk * CPX + lane;
    const int pi    = chunk >> 1;        // row (uniform per block)
    const int j0    = (chunk & 1) * 64;  // chunk's first column
    const int pj    = j0 + lane;

    // ---- issue weight global->LDS staging FIRST (per-wave region) ------
    {
        const float4* s4 = reinterpret_cast<const float4*>(
            wmap + ((size_t)(cls * NF + f) * PHI + chunk * CPX) * W27);
        float4* d4 = reinterpret_cast<float4*>(arena + f * (CPX * W27));
        #pragma unroll
        for (int i = 0; i < 7; ++i) {
            const int idx = lane + i * 64;           // 432 float4 per wave
            if (idx < (CPX * W27) / 4) d4[idx] = s4[idx];
        }
    }

    // ---- class membership (wave width == BSZ == 64); uniform exit ------
    const unsigned long long cmask = __ballot(cls_ids[lane] == cls);
    if (cmask == 0ULL) return;

    // ---- batch-invariant geometry --------------------------------------
    const int R0 = pi - 2, C0 = j0 - 2;              // unclamped tile origin
    const int CR0 = (pi - 2 < 0 ? 0 : pi - 2) >> 3;  // uniform cell rows
    const int CR1 = (pi + 2 > 127 ? 127 : pi + 2) >> 3;
    const int XC0 = (j0 - 2 < 0 ? 0 : j0 - 2) >> 3;  // uniform first cell col
    const int ccl0 = ((pj - 2 < 0 ? 0 : pj - 2) >> 3) - XC0;          // 0..9
    const int ccl1 = ((pj + 2 > 127 ? 127 : pj + 2) >> 3) - XC0;      // 0..9

    int ldsoff[KN], sel[KN];
    #pragma unroll
    for (int k = 0; k < KN; ++k) {
        const int n  = nb[p * KN + k];
        const int ni = n >> 7, nj = n & 127;         // always in [pi±2],[pj±2]
        ldsoff[k] = (ni - R0) * TW + (nj - C0);      // tile slot
        const int rr = ((ni >> 3) == CR0) ? 0 : 1;
        const int cc = ((nj >> 3) == (XC0 + ccl0)) ? 0 : 1;
        sel[k] = rr * 2 + cc;
    }
    int ldx[4];
    ldx[0] = f * 20 + ccl0;       ldx[1] = f * 20 + ccl1;
    ldx[2] = f * 20 + 10 + ccl0;  ldx[3] = f * 20 + 10 + ccl1;

    const float acc0 = bias_high[(cls * NF + f) * PHI + p];

    // ---- stager roles: tile slots t and 256+t; xs slot t ---------------
    int gO0 = 0, gO1 = 0;
    float bo00 = 0.f, bo01 = 0.f, bo10 = 0.f, bo11 = 0.f;
    {
        const int r = t / TW, c = t % TW;            // t < 256 <= 340
        int nr = R0 + r; nr = nr < 0 ? 0 : (nr > 127 ? 127 : nr);
        int nc = C0 + c; nc = nc < 0 ? 0 : (nc > 127 ? 127 : nc);
        const int ns = nr * 128 + nc;
        gO0  = ns * 8;
        bo00 = bias_orog[(cls * 2 + 0) * PHI + ns];
        bo01 = bias_orog[(cls * 2 + 1) * PHI + ns];
    }
    if (t < TSL - 256) {                             // slots 256..339
        const int s = 256 + t;
        const int r = s / TW, c = s % TW;
        int nr = R0 + r; nr = nr < 0 ? 0 : (nr > 127 ? 127 : nr);
        int nc = C0 + c; nc = nc < 0 ? 0 : (nc > 127 ? 127 : nc);
        const int ns = nr * 128 + nc;
        gO1  = ns * 8;
        bo10 = bias_orog[(cls * 2 + 0) * PHI + ns];
        bo11 = bias_orog[(cls * 2 + 1) * PHI + ns];
    }
    int xIdx = 0; float xbl = 0.f;
    if (t < XSL) {                                   // xs: (f, rr, cc)
        const int ff = t / 20, q = t % 20, rr = q / 10, cc = q % 10;
        const int crow = rr ? CR1 : CR0;
        int col = XC0 + cc; col = col > 15 ? 15 : col;
        xIdx = ff * PLO + crow * 16 + col;
        xbl  = bias_low[cls * (NF * PLO) + xIdx];
    }

    // ---- unpack this thread's weights + 9->4 y-weight collapse ---------
    float w1[KN], w2[KN], wcy[4] = {0.f, 0.f, 0.f, 0.f};
    #pragma unroll
    for (int k = 0; k < KN; ++k) {
        const float w0 = arena[f * (CPX * W27) + lane * W27 + 3 * k];
        w1[k] = arena[f * (CPX * W27) + lane * W27 + 3 * k + 1];
        w2[k] = arena[f * (CPX * W27) + lane * W27 + 3 * k + 2];
        #pragma unroll
        for (int j = 0; j < 4; ++j)
            wcy[j] += (sel[k] == j) ? w0 : 0.0f;
    }

    __syncthreads();                 // w-phase done; arena -> tile buffers

    float2* tb0 = reinterpret_cast<float2*>(arena);         // 340 float2
    float2* tb1 = reinterpret_cast<float2*>(arena + 680);   // 340 float2
    float*  xs0 = arena + 1360;                             // 80 floats
    float*  xs1 = arena + 1440;                             // 80 floats

    // ---- stage first batch ---------------------------------------------
    unsigned long long m = cmask;
    int b = __ffsll(m) - 1;  m &= m - 1;
    {
        const char* ob = (const char*)orog + (size_t)b * (PHI * 8);
        const float2 v0 = *reinterpret_cast<const float2*>(ob + gO0);
        tb0[t] = make_float2(v0.x - bo00, v0.y - bo01);
        if (t < TSL - 256) {
            const float2 v1 = *reinterpret_cast<const float2*>(ob + gO1);
            tb0[256 + t] = make_float2(v1.x - bo10, v1.y - bo11);
        }
        if (t < XSL) xs0[t] = x[b * (NF * PLO) + xIdx] - xbl;
    }
    __syncthreads();

    // ---- batch loop: double-buffered tiles, one barrier per iter -------
    int cur = 0;
    while (true) {
        const int bn = m ? (__ffsll(m) - 1) : -1;
        if (m) m &= m - 1;

        // issue next batch's staging loads (fly under current compute)
        float2 v0, v1; float xv;
        if (bn >= 0) {
            const char* ob = (const char*)orog + (size_t)bn * (PHI * 8);
            v0 = *reinterpret_cast<const float2*>(ob + gO0);
            if (t < TSL - 256) v1 = *reinterpret_cast<const float2*>(ob + gO1);
            if (t < XSL)       xv = x[bn * (NF * PLO) + xIdx];
        }

        // compute current batch from LDS
        const float2* tb = cur ? tb1 : tb0;
        const float*  xs = cur ? xs1 : xs0;
        float acc = acc0;
        #pragma unroll
        for (int j = 0; j < 4; ++j)
            acc += xs[ldx[j]] * wcy[j];
        #pragma unroll
        for (int k = 0; k < KN; ++k) {
            const float2 o = tb[ldsoff[k]];
            acc += o.x * w1[k] + o.y * w2[k];
        }
        out[((size_t)b * NF + f) * PHI + p] = acc;

        if (bn < 0) break;

        // write next batch's tiles (other buffer), then barrier
        float2* tbn = cur ? tb0 : tb1;
        float*  xsn = cur ? xs0 : xs1;
        tbn[t] = make_float2(v0.x - bo00, v0.y - bo01);
        if (t < TSL - 256) tbn[256 + t] = make_float2(v1.x - bo10, v1.y - bo11);
        if (t < XSL)       xsn[t] = xv - xbl;
        __syncthreads();

        b = bn; cur ^= 1;
    }
}

extern "C" void kernel_launch(void* const* d_in, const int* in_sizes, int n_in,
                              void* d_out, int out_size, void* d_ws, size_t ws_size,
                              hipStream_t stream) {
    const float* x         = (const float*)d_in[0];
    const float* orog      = (const float*)d_in[1];
    const float* wmap      = (const float*)d_in[2];
    const float* bias_low  = (const float*)d_in[3];
    const float* bias_high = (const float*)d_in[4];
    const float* bias_orog = (const float*)d_in[5];
    const int*   cls_ids   = (const int*)d_in[6];
    const int*   nb        = (const int*)d_in[7];
    float* out = (float*)d_out;

    // grid: NCLS classes x 256 chunks = 1024 blocks; block = 4 waves (f=wave)
    dim3 grid(NCLS * (PHI / CPX));
    dim3 block(256);
    rect_up_kernel<<<grid, block, 0, stream>>>(
        x, orog, wmap, bias_low, bias_high, bias_orog, cls_ids, nb, out);
}

// Round 9
// 25.110 us; speedup vs baseline: 4.4105x; 1.0037x over previous
//
#include <hip/hip_runtime.h>

#define BSZ    64
#define NF     4
#define NCLS   4
#define PLO    256
#define PHI    16384
#define KN     9
#define W27    27
#define CPX    64              // pixels per block (half a 128-row)
#define TH     5               // tile rows  (pi-2 .. pi+2)
#define TW     68              // tile cols  (j0-2 .. j0+65)
#define TSL    (TH * TW)       // 340 float2 slots
#define XSL    80              // NF * 2 cell-rows * 10 cell-cols
#define BUFF   1520            // floats per pair-buffer: 2*680 + 2*80
#define ARENA_F 6912           // floats: max(w-stage 4*1728, 2*BUFF=3040)

__global__ __launch_bounds__(256, 4) void rect_up_kernel(
    const float* __restrict__ x,         // (B, NF*PLO)
    const float* __restrict__ orog,      // (B, PHI, 2)
    const float* __restrict__ wmap,      // (NCLS, NF, PHI, KN, 3)
    const float* __restrict__ bias_low,  // (NCLS, NF, PLO)
    const float* __restrict__ bias_high, // (NCLS, NF, PHI)
    const float* __restrict__ bias_orog, // (NCLS, 2, PHI)
    const int*   __restrict__ cls_ids,   // (B,)
    const int*   __restrict__ nb,        // (PHI, KN)
    float* __restrict__ out)             // (B, NF, PHI)
{
    __shared__ float arena[ARENA_F];     // phase 1: w-stage; phase 2: tiles

    const int bid   = blockIdx.x;
    const int cls   = bid & 3;
    const int chunk = bid >> 2;          // 0..255
    const int t     = threadIdx.x;
    const int f     = t >> 6;            // wave == feature
    const int lane  = t & 63;
    const int p     = chunk * CPX + lane;
    const int pi    = chunk >> 1;        // row (uniform per block)
    const int j0    = (chunk & 1) * 64;  // chunk's first column
    const int pj    = j0 + lane;

    // ---- issue weight global->LDS staging FIRST (per-wave region) ------
    {
        const float4* s4 = reinterpret_cast<const float4*>(
            wmap + ((size_t)(cls * NF + f) * PHI + chunk * CPX) * W27);
        float4* d4 = reinterpret_cast<float4*>(arena + f * (CPX * W27));
        #pragma unroll
        for (int i = 0; i < 7; ++i) {
            const int idx = lane + i * 64;           // 432 float4 per wave
            if (idx < (CPX * W27) / 4) d4[idx] = s4[idx];
        }
    }

    // ---- class membership (wave width == BSZ == 64) --------------------
    const unsigned long long cmask = __ballot(cls_ids[lane] == cls);
    if (cmask == 0ULL) return;

    // ---- batch scan: first pair ----------------------------------------
    unsigned long long m = cmask;
    int b0 = __ffsll(m) - 1;  m &= m - 1;
    int b1 = m ? (__ffsll(m) - 1) : -1;  if (m) m &= m - 1;

    // ---- batch-invariant geometry --------------------------------------
    const int R0 = pi - 2, C0 = j0 - 2;              // unclamped tile origin
    const int CR0 = (pi - 2 < 0 ? 0 : pi - 2) >> 3;
    const int CR1 = (pi + 2 > 127 ? 127 : pi + 2) >> 3;
    const int XC0 = (j0 - 2 < 0 ? 0 : j0 - 2) >> 3;
    const int ccl0 = ((pj - 2 < 0 ? 0 : pj - 2) >> 3) - XC0;          // 0..9
    const int ccl1 = ((pj + 2 > 127 ? 127 : pj + 2) >> 3) - XC0;      // 0..9

    // ---- stager roles (tile slots t, 256+t; xs slot t) -----------------
    int gO0 = 0, gO1 = 0;
    float bo00, bo01, bo10 = 0.f, bo11 = 0.f;
    {
        const int r = t / TW, c = t % TW;            // t < 256 <= TSL
        int nr = R0 + r; nr = nr < 0 ? 0 : (nr > 127 ? 127 : nr);
        int nc = C0 + c; nc = nc < 0 ? 0 : (nc > 127 ? 127 : nc);
        const int ns = nr * 128 + nc;
        gO0  = ns * 8;
        bo00 = bias_orog[(cls * 2 + 0) * PHI + ns];
        bo01 = bias_orog[(cls * 2 + 1) * PHI + ns];
    }
    if (t < TSL - 256) {                             // slots 256..339
        const int s = 256 + t;
        const int r = s / TW, c = s % TW;
        int nr = R0 + r; nr = nr < 0 ? 0 : (nr > 127 ? 127 : nr);
        int nc = C0 + c; nc = nc < 0 ? 0 : (nc > 127 ? 127 : nc);
        const int ns = nr * 128 + nc;
        gO1  = ns * 8;
        bo10 = bias_orog[(cls * 2 + 0) * PHI + ns];
        bo11 = bias_orog[(cls * 2 + 1) * PHI + ns];
    }
    int xIdx = 0; float xbl = 0.f;
    if (t < XSL) {                                   // xs: (f, rr, cc)
        const int ff = t / 20, q = t % 20, rr = q / 10, cc = q % 10;
        const int crow = rr ? CR1 : CR0;
        int col = XC0 + cc; col = col > 15 ? 15 : col;
        xIdx = ff * PLO + crow * 16 + col;
        xbl  = bias_low[cls * (NF * PLO) + xIdx];
    }

    // ---- issue FIRST PAIR's tile loads now (hide under weight unpack) --
    float2 va0, va1; float xa = 0.f;
    float2 vb0, vb1; float xb = 0.f;
    {
        const char* ob = (const char*)orog + (size_t)b0 * (PHI * 8);
        va0 = *reinterpret_cast<const float2*>(ob + gO0);
        if (t < TSL - 256) va1 = *reinterpret_cast<const float2*>(ob + gO1);
        if (t < XSL)       xa  = x[b0 * (NF * PLO) + xIdx];
    }
    if (b1 >= 0) {
        const char* ob = (const char*)orog + (size_t)b1 * (PHI * 8);
        vb0 = *reinterpret_cast<const float2*>(ob + gO0);
        if (t < TSL - 256) vb1 = *reinterpret_cast<const float2*>(ob + gO1);
        if (t < XSL)       xb  = x[b1 * (NF * PLO) + xIdx];
    }

    // ---- per-pixel LDS offsets + cell selectors ------------------------
    int ldsoff[KN], sel[KN];
    #pragma unroll
    for (int k = 0; k < KN; ++k) {
        const int n  = nb[p * KN + k];
        const int ni = n >> 7, nj = n & 127;         // within [pi±2],[pj±2]
        ldsoff[k] = (ni - R0) * TW + (nj - C0);
        const int rr = ((ni >> 3) == CR0) ? 0 : 1;
        const int cc = ((nj >> 3) == (XC0 + ccl0)) ? 0 : 1;
        sel[k] = rr * 2 + cc;
    }
    int ldx[4];
    ldx[0] = f * 20 + ccl0;       ldx[1] = f * 20 + ccl1;
    ldx[2] = f * 20 + 10 + ccl0;  ldx[3] = f * 20 + 10 + ccl1;

    const float acc0 = bias_high[(cls * NF + f) * PHI + p];

    // ---- unpack this thread's weights + 9->4 y-weight collapse ---------
    float w1[KN], w2[KN], wcy[4] = {0.f, 0.f, 0.f, 0.f};
    #pragma unroll
    for (int k = 0; k < KN; ++k) {
        const float w0 = arena[f * (CPX * W27) + lane * W27 + 3 * k];
        w1[k] = arena[f * (CPX * W27) + lane * W27 + 3 * k + 1];
        w2[k] = arena[f * (CPX * W27) + lane * W27 + 3 * k + 2];
        #pragma unroll
        for (int j = 0; j < 4; ++j)
            wcy[j] += (sel[k] == j) ? w0 : 0.0f;
    }

    __syncthreads();                 // w-phase done; arena -> pair buffers

    // pair-buffer layout (floats): q*BUFF + { s*680 tile | 1360 + s*80 xs }
    // write first pair into buffer 0
    {
        float2* tb0 = reinterpret_cast<float2*>(arena);
        reinterpret_cast<float2*>(arena)[t] = make_float2(va0.x - bo00, va0.y - bo01);
        if (t < TSL - 256) tb0[256 + t] = make_float2(va1.x - bo10, va1.y - bo11);
        if (t < XSL) arena[1360 + t] = xa - xbl;
        if (b1 >= 0) {
            float2* tb1 = reinterpret_cast<float2*>(arena + 680);
            tb1[t] = make_float2(vb0.x - bo00, vb0.y - bo01);
            if (t < TSL - 256) tb1[256 + t] = make_float2(vb1.x - bo10, vb1.y - bo11);
            if (t < XSL) arena[1440 + t] = xb - xbl;
        }
    }
    __syncthreads();

    // ---- main loop: 2 batches per round, double-buffered ---------------
    int cur = 0;
    while (true) {
        // next pair
        int c0 = m ? (__ffsll(m) - 1) : -1;  if (m) m &= m - 1;
        int c1 = m ? (__ffsll(m) - 1) : -1;  if (m) m &= m - 1;

        // issue next pair's loads (fly under this pair's compute+stores)
        if (c0 >= 0) {
            const char* ob = (const char*)orog + (size_t)c0 * (PHI * 8);
            va0 = *reinterpret_cast<const float2*>(ob + gO0);
            if (t < TSL - 256) va1 = *reinterpret_cast<const float2*>(ob + gO1);
            if (t < XSL)       xa  = x[c0 * (NF * PLO) + xIdx];
        }
        if (c1 >= 0) {
            const char* ob = (const char*)orog + (size_t)c1 * (PHI * 8);
            vb0 = *reinterpret_cast<const float2*>(ob + gO0);
            if (t < TSL - 256) vb1 = *reinterpret_cast<const float2*>(ob + gO1);
            if (t < XSL)       xb  = x[c1 * (NF * PLO) + xIdx];
        }

        // compute current pair from LDS
        {
            const float* base = arena + cur * BUFF;
            const float2* tb = reinterpret_cast<const float2*>(base);
            const float*  xs = base + 1360;
            float acc = acc0;
            #pragma unroll
            for (int j = 0; j < 4; ++j) acc += xs[ldx[j]] * wcy[j];
            #pragma unroll
            for (int k = 0; k < KN; ++k) {
                const float2 o = tb[ldsoff[k]];
                acc += o.x * w1[k] + o.y * w2[k];
            }
            out[((size_t)b0 * NF + f) * PHI + p] = acc;
        }
        if (b1 >= 0) {
            const float* base = arena + cur * BUFF;
            const float2* tb = reinterpret_cast<const float2*>(base + 680);
            const float*  xs = base + 1440;
            float acc = acc0;
            #pragma unroll
            for (int j = 0; j < 4; ++j) acc += xs[ldx[j]] * wcy[j];
            #pragma unroll
            for (int k = 0; k < KN; ++k) {
                const float2 o = tb[ldsoff[k]];
                acc += o.x * w1[k] + o.y * w2[k];
            }
            out[((size_t)b1 * NF + f) * PHI + p] = acc;
        }

        if (c0 < 0) break;

        // write next pair into the other buffer, then one barrier
        {
            float* baseN = arena + (cur ^ 1) * BUFF;
            float2* tb0 = reinterpret_cast<float2*>(baseN);
            tb0[t] = make_float2(va0.x - bo00, va0.y - bo01);
            if (t < TSL - 256) tb0[256 + t] = make_float2(va1.x - bo10, va1.y - bo11);
            if (t < XSL) baseN[1360 + t] = xa - xbl;
            if (c1 >= 0) {
                float2* tb1 = reinterpret_cast<float2*>(baseN + 680);
                tb1[t] = make_float2(vb0.x - bo00, vb0.y - bo01);
                if (t < TSL - 256) tb1[256 + t] = make_float2(vb1.x - bo10, vb1.y - bo11);
                if (t < XSL) baseN[1440 + t] = xb - xbl;
            }
        }
        __syncthreads();

        b0 = c0; b1 = c1; cur ^= 1;
    }
}

extern "C" void kernel_launch(void* const* d_in, const int* in_sizes, int n_in,
                              void* d_out, int out_size, void* d_ws, size_t ws_size,
                              hipStream_t stream) {
    const float* x         = (const float*)d_in[0];
    const float* orog      = (const float*)d_in[1];
    const float* wmap      = (const float*)d_in[2];
    const float* bias_low  = (const float*)d_in[3];
    const float* bias_high = (const float*)d_in[4];
    const float* bias_orog = (const float*)d_in[5];
    const int*   cls_ids   = (const int*)d_in[6];
    const int*   nb        = (const int*)d_in[7];
    float* out = (float*)d_out;

    // grid: NCLS classes x 256 chunks = 1024 blocks; block = 4 waves (f=wave)
    dim3 grid(NCLS * (PHI / CPX));
    dim3 block(256);
    rect_up_kernel<<<grid, block, 0, stream>>>(
        x, orog, wmap, bias_low, bias_high, bias_orog, cls_ids, nb, out);
}